// Round 5
// baseline (558.440 us; speedup 1.0000x reference)
//
#include <hip/hip_runtime.h>
#include <hip/hip_bf16.h>

#define NN 4096      // n_nodes
#define FIN 1433     // in features
#define NH 8         // heads
#define DH 8         // per-head dim
#define HD 64        // NH*DH
#define KP 1472      // K padded to 46*32
#define LOG2E 1.44269504f
#define NJS 8        // j-splits: grid 2048 = exactly 8 blocks/CU
#define NCHK ((NN / NJS) / 128)   // 4 chunks of 128 j per block
#define NKS 4        // gemm K-splits: grid 1024 = 4 blocks/CU

typedef unsigned int u32;
typedef unsigned long long u64;
typedef float v4f __attribute__((ext_vector_type(4)));
typedef _Float16 f16;
typedef _Float16 h2 __attribute__((ext_vector_type(2)));
typedef _Float16 f16x8 __attribute__((ext_vector_type(8)));

static __device__ __forceinline__ short f2h16(float f) {
    union { f16 h; short s; } u; u.h = (f16)f; return u.s;
}
static __device__ __forceinline__ h2 u2h2(u32 x) {
    union { u32 u; h2 h; } v; v.u = x; return v.h;
}
static __device__ __forceinline__ u32 h22u(h2 x) {
    union { h2 h; u32 u; } v; v.h = x; return v.u;
}

#if __has_builtin(__builtin_amdgcn_sbfe)
#define SBFE1(x, k) __builtin_amdgcn_sbfe((int)(x), (k), 1)
#else
#define SBFE1(x, k) (((int)((x) << (31 - (k)))) >> 31)
#endif

// async global->LDS DMA, 16B per lane; LDS dest = wave-uniform base + lane*16.
static __device__ __forceinline__ void gload_lds16(const void* g, void* l) {
    __builtin_amdgcn_global_load_lds(
        (const __attribute__((address_space(1))) void*)g,
        (__attribute__((address_space(3))) void*)l, 16, 0, 0);
}

// ---------------- kernel 0: Wt prep + zero the last-arriver counters --------
__global__ __launch_bounds__(256) void k_wprep(const float* __restrict__ W,
                                               short* __restrict__ Wt,
                                               int* __restrict__ cnt) {
    __shared__ float Ts[64][65];
    const int c = blockIdx.x;
    const int u = threadIdx.x;
    if (c == 0) { cnt[u] = 0; cnt[256 + u] = 0; }   // cntG | cntA
    const int n4 = (u & 15) * 4;
    const int kr = u >> 4;
#pragma unroll
    for (int q = 0; q < 4; ++q) {
        const int kl = kr + q * 16;
        const int kg = c * 64 + kl;
        v4f v = {0.f, 0.f, 0.f, 0.f};
        if (kg < FIN) v = *(const v4f*)&W[(size_t)kg * HD + n4];
        *(v4f*)&Ts[kl][n4] = v;
    }
    __syncthreads();
    const int n = u >> 2;
    const int koff = (u & 3) * 16;
    __align__(16) short tmp[16];
#pragma unroll
    for (int r = 0; r < 16; ++r) tmp[r] = f2h16(Ts[koff + r][n]);
    *(uint4*)&Wt[(size_t)n * KP + c * 64 + koff]     = *(uint4*)&tmp[0];
    *(uint4*)&Wt[(size_t)n * KP + c * 64 + koff + 8] = *(uint4*)&tmp[8];
}

// ---------------- kernel 1: FUSED edge-compress + gemm-Ksplit + gpost --------
// R5: three kernels collapsed into one launch.
//  A) each block streams 4 edge rows -> emask (67 MB total, BW-bound,
//     overlapping all other phases across the 16 waves/CU)
//  B) R3's K-split GEMM slice -> Cp[ks]
//  C) last-arriver (counter cntG[ib]) reduces the 4 Cp slices with wave 0 and
//     runs the old k_gpost epilogue (gT/eB/eD/Rw).
__global__ __launch_bounds__(256, 4) void k_mid(
    const float* __restrict__ vert, const short* __restrict__ Wt,
    const int* __restrict__ edge,
    const float* __restrict__ al, const float* __restrict__ ar,
    float* __restrict__ Cp, uint4* __restrict__ emask,
    short* __restrict__ gT, short* __restrict__ eB, short* __restrict__ eD,
    float* __restrict__ Rw, int* __restrict__ cntG)
{
    __shared__ float cacc[4][16][68];   // 17.4 KB

    const int t = threadIdx.x, lane = t & 63, w = t >> 6;
    const int ml = lane & 15, q = lane >> 4;
    const int ib = blockIdx.x;          // i-block 0..255
    const int ks = blockIdx.y;          // K-split 0..3
    const int i0 = ib * 16;

    // ---- phase A: edge -> bitmask, rows 4b..4b+3 (b = ks*256+ib) ----------
    {
        const int b = ks * 256 + ib;
        for (int r = 0; r < 4; ++r) {
            const int row = b * 4 + r;
            const int* erow = edge + (size_t)row * NN;
            uint4* mrow = emask + (size_t)row * (NN / 128);
#pragma unroll
            for (int it = 0; it < 8; ++it) {
                const int ck = w * 8 + it;
                const int2 e2 = *(const int2*)&erow[ck * 128 + 2 * lane];
                const u64 bA = __ballot(e2.x != 0);
                const u64 bB = __ballot(e2.y != 0);
                if (lane == 0)
                    mrow[ck] = (uint4){(u32)bA, (u32)(bA >> 32),
                                       (u32)bB, (u32)(bB >> 32)};
            }
        }
    }

    // ---- phase B: gemm K-split slice -> Cp ---------------------------------
    const float* vrow = vert + (size_t)(i0 + ml) * FIN;
    v4f acc[4];
#pragma unroll
    for (int g = 0; g < 4; ++g) acc[g] = (v4f){0.f, 0.f, 0.f, 0.f};

    for (int c = ks + 4 * w; c < 45; c += 16) {
        const int k0 = c * 32 + q * 8;
        v4f a0, a1;
        if (k0 + 7 < FIN) {
            a0 = *(const v4f*)&vrow[k0];
            a1 = *(const v4f*)&vrow[k0 + 4];
        } else {
            float tmp[8];
#pragma unroll
            for (int e = 0; e < 8; ++e)
                tmp[e] = (k0 + e < FIN) ? vrow[k0 + e] : 0.f;
            a0 = (v4f){tmp[0], tmp[1], tmp[2], tmp[3]};
            a1 = (v4f){tmp[4], tmp[5], tmp[6], tmp[7]};
        }
        const f16x8 af = {(f16)a0.x, (f16)a0.y, (f16)a0.z, (f16)a0.w,
                          (f16)a1.x, (f16)a1.y, (f16)a1.z, (f16)a1.w};
#pragma unroll
        for (int g = 0; g < 4; ++g) {
            const f16x8 bf = *(const f16x8*)&Wt[(size_t)(g * 16 + ml) * KP + k0];
            acc[g] = __builtin_amdgcn_mfma_f32_16x16x32_f16(af, bf, acc[g], 0, 0, 0);
        }
    }

#pragma unroll
    for (int g = 0; g < 4; ++g)
#pragma unroll
        for (int r = 0; r < 4; ++r)
            cacc[w][q * 4 + r][g * 16 + ml] = acc[g][r];
    __syncthreads();

    {
        const int m = t >> 4, n4 = (t & 15) * 4;
        v4f s = (v4f){0.f, 0.f, 0.f, 0.f};
#pragma unroll
        for (int ww = 0; ww < 4; ++ww) s += *(const v4f*)&cacc[ww][m][n4];
        *(v4f*)&Cp[((size_t)ks * NN + i0 + m) * HD + n4] = s;
    }

    // ---- phase C: last arriver of the 4 K-splits does the epilogue ---------
    __threadfence();            // release this block's Cp slice
    __syncthreads();
    int old = 0;
    if (t == 0) old = atomicAdd(&cntG[ib], 1);
    if (w == 0) {
        old = __shfl(old, 0, 64);
        if (old == NKS - 1) {
            __threadfence();    // acquire all Cp slices
#pragma unroll
            for (int p = 0; p < 4; ++p) {
                const int u2 = p * 64 + lane;      // 0..255
                const int i = i0 + (u2 >> 4), n4 = (u2 & 15) * 4;
                v4f s = (v4f){0.f, 0.f, 0.f, 0.f};
#pragma unroll
                for (int kk = 0; kk < NKS; ++kk)
                    s += *(const v4f*)&Cp[((size_t)kk * NN + i) * HD + n4];
#pragma unroll
                for (int e = 0; e < 4; ++e)        // transposed: gT[hd][node]
                    gT[(size_t)(n4 + e) * NN + i] = f2h16(s[e]);
                float pl = s.x * al[n4] + s.y * al[n4 + 1]
                         + s.z * al[n4 + 2] + s.w * al[n4 + 3];
                float pr = s.x * ar[n4] + s.y * ar[n4 + 1]
                         + s.z * ar[n4 + 2] + s.w * ar[n4 + 3];
                pl += __shfl_xor(pl, 1, 64);
                pr += __shfl_xor(pr, 1, 64);
                if ((u2 & 1) == 0) {
                    const int h = (u2 & 15) >> 1;
                    eB[h * NN + i] = f2h16(exp2f(pr * LOG2E));
                    eD[h * NN + i] = f2h16(exp2f(0.2f * pr * LOG2E));
                    Rw[i * NH + h] = exp2f(-0.8f * pl * LOG2E);
                }
            }
        }
    }
}

// ---------------- kernel 2: MFMA flash-attn (R4 core) + fused combine --------
// R4-validated DMA-staged core, byte-identical. Tail: last arriver of the 8
// j-splits (counter cntA[ib]) computes div+ELU for its 16 rows with wave 0.
__global__ __launch_bounds__(256, 8) void k_attn(
    const uint4* __restrict__ emask, const short* __restrict__ gT,
    const short* __restrict__ eB, const short* __restrict__ eD,
    const float* __restrict__ Rw,
    float* __restrict__ numw, float* __restrict__ denw,
    float* __restrict__ out, int* __restrict__ cntA)
{
    __shared__ __align__(16) short Gs[64 * 128];   // 16 KB swizzled G chunk
    __shared__ __align__(16) short BDs[8 * 256];   // 4 KB: [h][B:128|D:128]

    const int t = threadIdx.x, lane = t & 63, w = t >> 6;
    const int ml = lane & 15, quad = lane >> 4;
    const int m8 = ml & 7;
    const int ib = blockIdx.x;
    const int i0 = ib * 16;
    const int js = blockIdx.y;
    const int jbase = js * (NN / NJS);
    const int h0 = w, h1 = w + 4;
    const int qb4 = quad * 4;
    const bool mhi = (ml >= 8);
    const u32 one2 = 0x3C003C00u;                   // f16 {1.0, 1.0}
    const uint4 ones4 = (uint4){one2, one2, one2, one2};

    h2 Ri[2];
    {
        const f16 r0 = (f16)Rw[(i0 + ml) * NH + h0];
        const f16 r1 = (f16)Rw[(i0 + ml) * NH + h1];
        Ri[0] = (h2){r0, r0};
        Ri[1] = (h2){r1, r1};
    }

    const uint4* mrow = emask + (size_t)(i0 + ml) * (NN / 128) + js * NCHK;

    const short* gsrc[4];
#pragma unroll
    for (int r = 0; r < 4; ++r) {
        const int u = r * 256 + t;
        const int row = u >> 4;
        const int col = ((u & 15) * 8) ^ ((row & 7) * 8);
        gsrc[r] = gT + (size_t)row * NN + jbase + col;
    }
    const int bh2 = t >> 5, bk = t & 31;
    const short* bdsrc = (bk < 16 ? eB : eD) + (size_t)bh2 * NN + jbase + (bk & 15) * 8;
    char* const bddst = (char*)BDs + (t & ~63) * 16;

    v4f acc[2];
    acc[0] = (v4f){0.f, 0.f, 0.f, 0.f};
    acc[1] = (v4f){0.f, 0.f, 0.f, 0.f};

    for (int c = 0; c < NCHK; ++c) {
        const int jc = c * 128;
#pragma unroll
        for (int r = 0; r < 4; ++r)
            gload_lds16(gsrc[r] + jc, (char*)Gs + r * 4096 + (t & ~63) * 16);
        gload_lds16(bdsrc + jc, bddst);
        const uint4 mw = mrow[c];             // 128 mask bits for this chunk
        __syncthreads();                      // drains vmcnt -> LDS valid
#pragma unroll
        for (int s = 0; s < 4; ++s) {
            const int xj = s * 32 + quad * 8;
            const int xg = xj ^ (m8 * 8);     // read-side swizzle
            const uint4 gu0 = *(const uint4*)&Gs[(h0 * 8 + m8) * 128 + xg];
            const uint4 gu1 = *(const uint4*)&Gs[(h1 * 8 + m8) * 128 + xg];
            const uint4 bu0 = *(const uint4*)&BDs[h0 * 256 + xj];
            const uint4 du0 = *(const uint4*)&BDs[h0 * 256 + 128 + xj];
            const uint4 bu1 = *(const uint4*)&BDs[h1 * 256 + xj];
            const uint4 du1 = *(const uint4*)&BDs[h1 * 256 + 128 + xj];
            const int base = ((s & 1) << 4) + qb4;
            const u32 WA = ((s >> 1) ? mw.y : mw.x) >> base;   // even-j bits
            const u32 WB = ((s >> 1) ? mw.w : mw.z) >> base;   // odd-j bits
            u32 m[4];
#pragma unroll
            for (int k = 0; k < 4; ++k) {
                const int ea = SBFE1(WA, k);            // 0 or 0xFFFFFFFF
                const int eb = SBFE1(WB, k);
                m[k] = __builtin_amdgcn_perm((u32)eb, (u32)ea, 0x05040100u);
            }
            u32 aw0[4], aw1[4];
#pragma unroll
            for (int k = 0; k < 4; ++k) {
                const u32 rd0 = h22u(Ri[0] * u2h2((&du0.x)[k]));   // v_pk_mul_f16
                const u32 rd1 = h22u(Ri[1] * u2h2((&du1.x)[k]));
                u32 p0, p1;
                asm("v_pk_max_f16 %0, %1, %2" : "=v"(p0) : "v"(rd0), "v"((&bu0.x)[k]));
                asm("v_pk_max_f16 %0, %1, %2" : "=v"(p1) : "v"(rd1), "v"((&bu1.x)[k]));
                aw0[k] = p0 & m[k];
                aw1[k] = p1 & m[k];
            }
            union { uint4 u; f16x8 h; } a0u, a1u, g0u, g1u;
            a0u.u = (uint4){aw0[0], aw0[1], aw0[2], aw0[3]};
            a1u.u = (uint4){aw1[0], aw1[1], aw1[2], aw1[3]};
            g0u.u = mhi ? ones4 : gu0;            // col 8 = ones (denominator)
            g1u.u = mhi ? ones4 : gu1;
            acc[0] = __builtin_amdgcn_mfma_f32_16x16x32_f16(a0u.h, g0u.h, acc[0], 0, 0, 0);
            acc[1] = __builtin_amdgcn_mfma_f32_16x16x32_f16(a1u.h, g1u.h, acc[1], 0, 0, 0);
        }
        __syncthreads();                      // all waves done reading LDS
    }

    // partial store: col = ml (0..7 dims, 8 = denominator), row = quad*4 + r
    float* nw = numw + (size_t)js * NN * HD;
    float* dw = denw + (size_t)js * NN * NH;
    const int ibase = i0 + quad * 4;
#pragma unroll
    for (int hh = 0; hh < 2; ++hh) {
        const int h = w + hh * 4;
#pragma unroll
        for (int r = 0; r < 4; ++r) {
            if (ml < 8)       nw[(ibase + r) * HD + h * 8 + ml] = acc[hh][r];
            else if (ml == 8) dw[(ibase + r) * NH + h]          = acc[hh][r];
        }
    }

    // ---- fused combine: last arriver of the 8 j-splits, wave 0 only --------
    __threadfence();            // release this block's partials
    __syncthreads();
    int old = 0;
    if (t == 0) old = atomicAdd(&cntA[ib], 1);
    if (w == 0) {
        old = __shfl(old, 0, 64);
        if (old == NJS - 1) {
            __threadfence();    // acquire all partials
#pragma unroll
            for (int p = 0; p < 16; ++p) {
                const int row = i0 + p;
                const int hh = lane >> 3;
                float num = 0.f, den = 0.f;
#pragma unroll
                for (int s = 0; s < NJS; ++s) {
                    num += numw[(size_t)s * NN * HD + row * HD + lane];
                    den += denw[(size_t)s * NN * NH + row * NH + hh];
                }
                const float x = num / den;
                out[row * HD + lane] = (x > 0.f) ? x : (__expf(x) - 1.f);
            }
        }
    }
}

extern "C" void kernel_launch(void* const* d_in, const int* in_sizes, int n_in,
                              void* d_out, int out_size, void* d_ws, size_t ws_size,
                              hipStream_t stream) {
    const float* vert = (const float*)d_in[0];
    const int*   edge = (const int*)d_in[1];
    const float* W    = (const float*)d_in[2];
    const float* al   = (const float*)d_in[3];
    const float* ar   = (const float*)d_in[4];
    float* out = (float*)d_out;

    char* ws = (char*)d_ws;
    short* gT    = (short*)ws;                          // 512 KB f16 g^T
    short* eB    = (short*)(ws + 512 * 1024);           // 64 KB
    short* eD    = (short*)(ws + 576 * 1024);           // 64 KB
    float* Rw    = (float*)(ws + 640 * 1024);           // 128 KB
    short* Wt    = (short*)(ws + 768 * 1024);           // 184 KB
    uint4* emask = (uint4*)(ws + 1024 * 1024);          // 2 MB edge bitmask
    float* Cp    = (float*)(ws + 3 * 1024 * 1024);      // 4 MB gemm K-partials
    float* numw  = (float*)(ws + 7 * 1024 * 1024);      // 8 MB (8 j-splits)
    float* denw  = (float*)(ws + 15 * 1024 * 1024);     // 1 MB
    int*   cnt   = (int*)(ws + 16 * 1024 * 1024);       // 2 KB counters

    hipLaunchKernelGGL(k_wprep, dim3(23), dim3(256), 0, stream, W, Wt, cnt);
    hipLaunchKernelGGL(k_mid, dim3(NN / 16, NKS), dim3(256), 0, stream,
                       vert, Wt, edge, al, ar, Cp, emask, gT, eB, eD, Rw, cnt);
    hipLaunchKernelGGL(k_attn, dim3(NN / 16, NJS), dim3(256), 0, stream,
                       emask, gT, eB, eD, Rw, numw, denw, out, cnt + 256);
}

// Round 6
// 166.990 us; speedup vs baseline: 3.3441x; 3.3441x over previous
//
#include <hip/hip_runtime.h>
#include <hip/hip_bf16.h>

#define NN 4096      // n_nodes
#define FIN 1433     // in features
#define NH 8         // heads
#define DH 8         // per-head dim
#define HD 64        // NH*DH
#define KP 1472      // K padded to 46*32
#define LOG2E 1.44269504f
#define NJS 8        // j-splits: grid 2048 = exactly 8 blocks/CU
#define NCHK ((NN / NJS) / 64)    // 8 chunks of 64 j per block
#define NKS 4        // gemm K-splits: grid 1024 = 4 blocks/CU

typedef unsigned int u32;
typedef unsigned long long u64;
typedef float v4f __attribute__((ext_vector_type(4)));
typedef _Float16 f16;
typedef _Float16 h2 __attribute__((ext_vector_type(2)));
typedef _Float16 f16x8 __attribute__((ext_vector_type(8)));

static __device__ __forceinline__ short f2h16(float f) {
    union { f16 h; short s; } u; u.h = (f16)f; return u.s;
}
static __device__ __forceinline__ h2 u2h2(u32 x) {
    union { u32 u; h2 h; } v; v.u = x; return v.h;
}
static __device__ __forceinline__ u32 h22u(h2 x) {
    union { h2 h; u32 u; } v; v.h = x; return v.u;
}

#if __has_builtin(__builtin_amdgcn_sbfe)
#define SBFE1(x, k) __builtin_amdgcn_sbfe((int)(x), (k), 1)
#else
#define SBFE1(x, k) (((int)((x) << (31 - (k)))) >> 31)
#endif

// async global->LDS DMA, 16B per lane; LDS dest = wave-uniform base + lane*16.
static __device__ __forceinline__ void gload_lds16(const void* g, void* l) {
    __builtin_amdgcn_global_load_lds(
        (const __attribute__((address_space(1))) void*)g,
        (__attribute__((address_space(3))) void*)l, 16, 0, 0);
}

// ---------------- kernel 0: Wt[n][k] = f16(W[k][n]), k zero-padded to 1472 ---
__global__ __launch_bounds__(256) void k_wprep(const float* __restrict__ W,
                                               short* __restrict__ Wt) {
    __shared__ float Ts[64][65];
    const int c = blockIdx.x;
    const int u = threadIdx.x;
    const int n4 = (u & 15) * 4;
    const int kr = u >> 4;
#pragma unroll
    for (int q = 0; q < 4; ++q) {
        const int kl = kr + q * 16;
        const int kg = c * 64 + kl;
        v4f v = {0.f, 0.f, 0.f, 0.f};
        if (kg < FIN) v = *(const v4f*)&W[(size_t)kg * HD + n4];
        *(v4f*)&Ts[kl][n4] = v;
    }
    __syncthreads();
    const int n = u >> 2;
    const int koff = (u & 3) * 16;
    __align__(16) short tmp[16];
#pragma unroll
    for (int r = 0; r < 16; ++r) tmp[r] = f2h16(Ts[koff + r][n]);
    *(uint4*)&Wt[(size_t)n * KP + c * 64 + koff]     = *(uint4*)&tmp[0];
    *(uint4*)&Wt[(size_t)n * KP + c * 64 + koff + 8] = *(uint4*)&tmp[8];
}

// ---------------- kernel 1: FUSED edge-compress + gemm K-split ---------------
// R6: eprep fused as phase A (NO cross-block sync anywhere — emask/Cp are
// consumed by LATER launches, stream-ordered). Mask uint4 field order is now
// {A_lo, B_lo, A_hi, B_hi} so k_attn reads a uint2 per 64-j chunk.
__global__ __launch_bounds__(256, 4) void k_mid(
    const float* __restrict__ vert, const short* __restrict__ Wt,
    const int* __restrict__ edge,
    float* __restrict__ Cp, uint4* __restrict__ emask)
{
    __shared__ float cacc[4][16][68];   // 17.4 KB

    const int t = threadIdx.x, lane = t & 63, w = t >> 6;
    const int ml = lane & 15, q = lane >> 4;
    const int ib = blockIdx.x;          // i-block 0..255
    const int ks = blockIdx.y;          // K-split 0..3
    const int i0 = ib * 16;

    // ---- phase A: edge -> bitmask, rows 4b..4b+3 (b = ks*256+ib) -----------
    {
        const int b = ks * 256 + ib;
        for (int r = 0; r < 4; ++r) {
            const int row = b * 4 + r;
            const int* erow = edge + (size_t)row * NN;
            uint4* mrow = emask + (size_t)row * (NN / 128);
#pragma unroll
            for (int it = 0; it < 8; ++it) {
                const int ck = w * 8 + it;
                const int2 e2 = *(const int2*)&erow[ck * 128 + 2 * lane];
                const u64 bA = __ballot(e2.x != 0);
                const u64 bB = __ballot(e2.y != 0);
                if (lane == 0)
                    mrow[ck] = (uint4){(u32)bA, (u32)bB,
                                       (u32)(bA >> 32), (u32)(bB >> 32)};
            }
        }
    }

    // ---- phase B: gemm K-split slice -> Cp ----------------------------------
    const float* vrow = vert + (size_t)(i0 + ml) * FIN;
    v4f acc[4];
#pragma unroll
    for (int g = 0; g < 4; ++g) acc[g] = (v4f){0.f, 0.f, 0.f, 0.f};

    for (int c = ks + 4 * w; c < 45; c += 16) {
        const int k0 = c * 32 + q * 8;
        v4f a0, a1;
        if (k0 + 7 < FIN) {
            a0 = *(const v4f*)&vrow[k0];
            a1 = *(const v4f*)&vrow[k0 + 4];
        } else {
            float tmp[8];
#pragma unroll
            for (int e = 0; e < 8; ++e)
                tmp[e] = (k0 + e < FIN) ? vrow[k0 + e] : 0.f;
            a0 = (v4f){tmp[0], tmp[1], tmp[2], tmp[3]};
            a1 = (v4f){tmp[4], tmp[5], tmp[6], tmp[7]};
        }
        const f16x8 af = {(f16)a0.x, (f16)a0.y, (f16)a0.z, (f16)a0.w,
                          (f16)a1.x, (f16)a1.y, (f16)a1.z, (f16)a1.w};
#pragma unroll
        for (int g = 0; g < 4; ++g) {
            const f16x8 bf = *(const f16x8*)&Wt[(size_t)(g * 16 + ml) * KP + k0];
            acc[g] = __builtin_amdgcn_mfma_f32_16x16x32_f16(af, bf, acc[g], 0, 0, 0);
        }
    }

#pragma unroll
    for (int g = 0; g < 4; ++g)
#pragma unroll
        for (int r = 0; r < 4; ++r)
            cacc[w][q * 4 + r][g * 16 + ml] = acc[g][r];
    __syncthreads();

    const int m = t >> 4, n4 = (t & 15) * 4;
    v4f s = (v4f){0.f, 0.f, 0.f, 0.f};
#pragma unroll
    for (int ww = 0; ww < 4; ++ww) s += *(const v4f*)&cacc[ww][m][n4];
    *(v4f*)&Cp[((size_t)ks * NN + i0 + m) * HD + n4] = s;
}

// ---------------- kernel 1b: reduce K-partials + epilogue --------------------
__global__ __launch_bounds__(256) void k_gpost(
    const float* __restrict__ Cp,
    const float* __restrict__ al, const float* __restrict__ ar,
    short* __restrict__ gT, short* __restrict__ eB, short* __restrict__ eD,
    float* __restrict__ Rw)
{
    const int t = threadIdx.x;
    const int gid = blockIdx.x * 256 + t;        // 0 .. NN*16-1
    const int i = gid >> 4, n4 = (gid & 15) * 4;

    v4f s = (v4f){0.f, 0.f, 0.f, 0.f};
#pragma unroll
    for (int ks = 0; ks < NKS; ++ks)
        s += *(const v4f*)&Cp[((size_t)ks * NN + i) * HD + n4];

#pragma unroll
    for (int e = 0; e < 4; ++e)        // transposed store: gT[hd][node]
        gT[(size_t)(n4 + e) * NN + i] = f2h16(s[e]);

    float pl = s.x * al[n4] + s.y * al[n4 + 1] + s.z * al[n4 + 2] + s.w * al[n4 + 3];
    float pr = s.x * ar[n4] + s.y * ar[n4 + 1] + s.z * ar[n4 + 2] + s.w * ar[n4 + 3];
    pl += __shfl_xor(pl, 1, 64);
    pr += __shfl_xor(pr, 1, 64);
    if ((t & 1) == 0) {
        const int h = (t & 15) >> 1;
        eB[h * NN + i] = f2h16(exp2f(pr * LOG2E));          // exp(sr)
        eD[h * NN + i] = f2h16(exp2f(0.2f * pr * LOG2E));   // exp(0.2 sr)
        Rw[i * NH + h] = exp2f(-0.8f * pl * LOG2E);         // exp(-0.8 sl)
    }
}

// ---------------- kernel 2: MFMA flash-attn, 64j-dbuf DMA, 8 blocks/CU -------
// R6: 64-j chunks, DOUBLE-buffered DMA staging, ONE barrier per chunk:
//   barrier (vmcnt(0) drains prev-issued DMA -> buf[cb] valid, nb free)
//   issue DMA(c+1 -> nb)            <- latency hides under compute(c)
//   compute(c) on buf[cb]
// LDS 2x(8K G + 2K BD) = 20 KB -> still exactly 8 blocks/CU. R4's schedule
// exposed full DMA latency between its two barriers; this one doesn't.
// NO device-scope fences anywhere (R5 lesson).
__global__ __launch_bounds__(256, 8) void k_attn(
    const uint4* __restrict__ emask, const short* __restrict__ gT,
    const short* __restrict__ eB, const short* __restrict__ eD,
    const float* __restrict__ Rw,
    float* __restrict__ numw, float* __restrict__ denw)
{
    __shared__ __align__(16) short Gs[2][64 * 64];   // 2 x 8 KB, XOR-swizzled
    __shared__ __align__(16) short BDs[2][8 * 128];  // 2 x 2 KB: [h][B:64|D:64]

    const int t = threadIdx.x, lane = t & 63, w = t >> 6;
    const int ml = lane & 15, quad = lane >> 4;
    const int m8 = ml & 7;
    const int i0 = blockIdx.x * 16;
    const int js = blockIdx.y;
    const int jbase = js * (NN / NJS);
    const int h0 = w, h1 = w + 4;
    const int qb4 = quad * 4;
    const bool mhi = (ml >= 8);
    const u32 one2 = 0x3C003C00u;                   // f16 {1.0, 1.0}
    const uint4 ones4 = (uint4){one2, one2, one2, one2};

    h2 Ri[2];
    {
        const f16 r0 = (f16)Rw[(i0 + ml) * NH + h0];
        const f16 r1 = (f16)Rw[(i0 + ml) * NH + h1];
        Ri[0] = (h2){r0, r0};
        Ri[1] = (h2){r1, r1};
    }

    // per-64j-chunk mask: uint2 {A word, B word} (field order set by k_mid)
    const uint2* mrow = (const uint2*)emask + (size_t)(i0 + ml) * (NN / 64) + js * NCHK;

    // G staging: units u = t and 256+t; row = u>>3, col = (u&7)*8 ^ (row&7)*8
    const short *gsrc0, *gsrc1;
    {
        int u = t, row = u >> 3;
        gsrc0 = gT + (size_t)row * NN + jbase + (((u & 7) * 8) ^ ((row & 7) * 8));
        u = 256 + t; row = u >> 3;
        gsrc1 = gT + (size_t)row * NN + jbase + (((u & 7) * 8) ^ ((row & 7) * 8));
    }
    // BD staging (waves 0,1 only): unit t -> head t>>4, slot t&15 (0-7 B, 8-15 D)
    const short* bdsrc = nullptr;
    if (t < 128) {
        const int head = t >> 4, slot = t & 15;
        bdsrc = (slot < 8 ? eB : eD) + (size_t)head * NN + jbase + (slot & 7) * 8;
    }
    const int wub = (t & ~63) * 16;                  // wave-uniform dest base

#define STAGE(buf, ck)                                                        \
    do {                                                                      \
        const int jc_ = (ck) * 64;                                            \
        gload_lds16(gsrc0 + jc_, (char*)Gs[buf] + wub);                       \
        gload_lds16(gsrc1 + jc_, (char*)Gs[buf] + 4096 + wub);                \
        if (t < 128) gload_lds16(bdsrc + jc_, (char*)BDs[buf] + wub);         \
    } while (0)

    v4f acc[2];
    acc[0] = (v4f){0.f, 0.f, 0.f, 0.f};
    acc[1] = (v4f){0.f, 0.f, 0.f, 0.f};

    STAGE(0, 0);
    uint2 mw = mrow[0], pm;

    for (int c = 0; c < NCHK; ++c) {
        const int cb = c & 1, nb = cb ^ 1;
        __syncthreads();                  // drains vmcnt -> buf[cb] valid, nb free
        const bool pf = (c + 1) < NCHK;
        if (pf) { STAGE(nb, c + 1); pm = mrow[c + 1]; }
#pragma unroll
        for (int s = 0; s < 2; ++s) {
            const int xj = s * 32 + quad * 8;          // 0..56
            const int xg = xj ^ (m8 * 8);              // read-side swizzle
            const uint4 gu0 = *(const uint4*)&Gs[cb][(h0 * 8 + m8) * 64 + xg];
            const uint4 gu1 = *(const uint4*)&Gs[cb][(h1 * 8 + m8) * 64 + xg];
            const uint4 bu0 = *(const uint4*)&BDs[cb][h0 * 128 + xj];
            const uint4 du0 = *(const uint4*)&BDs[cb][h0 * 128 + 64 + xj];
            const uint4 bu1 = *(const uint4*)&BDs[cb][h1 * 128 + xj];
            const uint4 du1 = *(const uint4*)&BDs[cb][h1 * 128 + 64 + xj];
            const int base = (s << 4) + qb4;
            const u32 WA = mw.x >> base;               // even-j bits
            const u32 WB = mw.y >> base;               // odd-j bits
            u32 m[4];
#pragma unroll
            for (int k = 0; k < 4; ++k) {
                const int ea = SBFE1(WA, k);           // 0 or 0xFFFFFFFF
                const int eb = SBFE1(WB, k);
                m[k] = __builtin_amdgcn_perm((u32)eb, (u32)ea, 0x05040100u);
            }
            u32 aw0[4], aw1[4];
#pragma unroll
            for (int k = 0; k < 4; ++k) {
                const u32 rd0 = h22u(Ri[0] * u2h2((&du0.x)[k]));   // v_pk_mul_f16
                const u32 rd1 = h22u(Ri[1] * u2h2((&du1.x)[k]));
                u32 p0, p1;
                asm("v_pk_max_f16 %0, %1, %2" : "=v"(p0) : "v"(rd0), "v"((&bu0.x)[k]));
                asm("v_pk_max_f16 %0, %1, %2" : "=v"(p1) : "v"(rd1), "v"((&bu1.x)[k]));
                aw0[k] = p0 & m[k];
                aw1[k] = p1 & m[k];
            }
            union { uint4 u; f16x8 h; } a0u, a1u, g0u, g1u;
            a0u.u = (uint4){aw0[0], aw0[1], aw0[2], aw0[3]};
            a1u.u = (uint4){aw1[0], aw1[1], aw1[2], aw1[3]};
            g0u.u = mhi ? ones4 : gu0;            // col 8 = ones (denominator)
            g1u.u = mhi ? ones4 : gu1;
            acc[0] = __builtin_amdgcn_mfma_f32_16x16x32_f16(a0u.h, g0u.h, acc[0], 0, 0, 0);
            acc[1] = __builtin_amdgcn_mfma_f32_16x16x32_f16(a1u.h, g1u.h, acc[1], 0, 0, 0);
        }
        if (pf) mw = pm;
    }
#undef STAGE

    // partial store: col = ml (0..7 dims, 8 = denominator), row = quad*4 + r
    float* nw = numw + (size_t)js * NN * HD;
    float* dw = denw + (size_t)js * NN * NH;
    const int ibase = i0 + quad * 4;
#pragma unroll
    for (int hh = 0; hh < 2; ++hh) {
        const int h = w + hh * 4;
#pragma unroll
        for (int r = 0; r < 4; ++r) {
            if (ml < 8)       nw[(ibase + r) * HD + h * 8 + ml] = acc[hh][r];
            else if (ml == 8) dw[(ibase + r) * NH + h]          = acc[hh][r];
        }
    }
}

// ---------------- kernel 3: combine j-split partials, div, ELU ---------------
__global__ __launch_bounds__(256) void k_comb(
    const float* __restrict__ numw, const float* __restrict__ denw,
    float* __restrict__ out)
{
    const int gid = blockIdx.x * 256 + threadIdx.x;   // 0 .. NN*HD-1
    const int i = gid >> 6, h = (gid & 63) >> 3;
    float num = 0.f, den = 0.f;
#pragma unroll
    for (int s = 0; s < NJS; ++s) {
        num += numw[(size_t)s * NN * HD + gid];
        den += denw[(size_t)s * NN * NH + i * NH + h];
    }
    float x = num / den;
    out[gid] = (x > 0.f) ? x : (__expf(x) - 1.f);     // ELU
}

extern "C" void kernel_launch(void* const* d_in, const int* in_sizes, int n_in,
                              void* d_out, int out_size, void* d_ws, size_t ws_size,
                              hipStream_t stream) {
    const float* vert = (const float*)d_in[0];
    const int*   edge = (const int*)d_in[1];
    const float* W    = (const float*)d_in[2];
    const float* al   = (const float*)d_in[3];
    const float* ar   = (const float*)d_in[4];
    float* out = (float*)d_out;

    char* ws = (char*)d_ws;
    short* gT    = (short*)ws;                          // 512 KB f16 g^T
    short* eB    = (short*)(ws + 512 * 1024);           // 64 KB
    short* eD    = (short*)(ws + 576 * 1024);           // 64 KB
    float* Rw    = (float*)(ws + 640 * 1024);           // 128 KB
    short* Wt    = (short*)(ws + 768 * 1024);           // 184 KB
    uint4* emask = (uint4*)(ws + 1024 * 1024);          // 2 MB edge bitmask
    float* Cp    = (float*)(ws + 3 * 1024 * 1024);      // 4 MB gemm K-partials
    float* numw  = (float*)(ws + 7 * 1024 * 1024);      // 8 MB (8 j-splits)
    float* denw  = (float*)(ws + 15 * 1024 * 1024);     // 1 MB

    hipLaunchKernelGGL(k_wprep, dim3(23), dim3(256), 0, stream, W, Wt);
    hipLaunchKernelGGL(k_mid, dim3(NN / 16, NKS), dim3(256), 0, stream,
                       vert, Wt, edge, Cp, emask);
    hipLaunchKernelGGL(k_gpost, dim3(NN * 16 / 256), dim3(256), 0, stream,
                       Cp, al, ar, gT, eB, eD, Rw);
    hipLaunchKernelGGL(k_attn, dim3(NN / 16, NJS), dim3(256), 0, stream,
                       emask, gT, eB, eD, Rw, numw, denw);
    hipLaunchKernelGGL(k_comb, dim3(NN * HD / 256), dim3(256), 0, stream,
                       numw, denw, out);
}

// Round 7
// 154.757 us; speedup vs baseline: 3.6085x; 1.0791x over previous
//
#include <hip/hip_runtime.h>
#include <hip/hip_bf16.h>

#define NN 4096      // n_nodes
#define FIN 1433     // in features
#define NH 8         // heads
#define DH 8         // per-head dim
#define HD 64        // NH*DH
#define KP 1472      // K padded to 46*32
#define LOG2E 1.44269504f
#define NJS 8        // j-splits
#define ITB 32       // i-rows per attn block (R7: 16 -> 32, 2x work/barrier)
#define NCHK ((NN / NJS) / 64)    // 8 chunks of 64 j per block
#define NKS 4        // gemm K-splits: grid 1024 = 4 blocks/CU

typedef unsigned int u32;
typedef unsigned long long u64;
typedef float v4f __attribute__((ext_vector_type(4)));
typedef _Float16 f16;
typedef _Float16 h2 __attribute__((ext_vector_type(2)));
typedef _Float16 f16x8 __attribute__((ext_vector_type(8)));

static __device__ __forceinline__ short f2h16(float f) {
    union { f16 h; short s; } u; u.h = (f16)f; return u.s;
}
static __device__ __forceinline__ h2 u2h2(u32 x) {
    union { u32 u; h2 h; } v; v.u = x; return v.h;
}
static __device__ __forceinline__ u32 h22u(h2 x) {
    union { h2 h; u32 u; } v; v.h = x; return v.u;
}

#if __has_builtin(__builtin_amdgcn_sbfe)
#define SBFE1(x, k) __builtin_amdgcn_sbfe((int)(x), (k), 1)
#else
#define SBFE1(x, k) (((int)((x) << (31 - (k)))) >> 31)
#endif

// async global->LDS DMA, 16B per lane; LDS dest = wave-uniform base + lane*16.
static __device__ __forceinline__ void gload_lds16(const void* g, void* l) {
    __builtin_amdgcn_global_load_lds(
        (const __attribute__((address_space(1))) void*)g,
        (__attribute__((address_space(3))) void*)l, 16, 0, 0);
}

// ---------------- kernel e: edge -> bitmask (standalone again, R6 lesson) ----
// Grid 4096 = 16 blocks/CU: the 67 MB stream needs its own high-TLP launch.
// Word order {A_lo, B_lo, A_hi, B_hi}: k_attn reads a uint2 per 64-j chunk.
__global__ __launch_bounds__(256) void k_eprep(const int* __restrict__ edge,
                                               uint4* __restrict__ emask) {
    const int t = threadIdx.x, lane = t & 63, w = t >> 6;
    const int row = blockIdx.x;
    const int* erow = edge + (size_t)row * NN;
    uint4* mrow = emask + (size_t)row * (NN / 128);
#pragma unroll
    for (int it = 0; it < 8; ++it) {
        const int ck = w * 8 + it;            // 4 waves x 8 = 32 chunks/row
        const int2 e2 = *(const int2*)&erow[ck * 128 + 2 * lane];
        const u64 bA = __ballot(e2.x != 0);
        const u64 bB = __ballot(e2.y != 0);
        if (lane == 0)
            mrow[ck] = (uint4){(u32)bA, (u32)bB, (u32)(bA >> 32), (u32)(bB >> 32)};
    }
}

// ---------------- kernel 0: Wt[n][k] = f16(W[k][n]), k zero-padded to 1472 ---
__global__ __launch_bounds__(256) void k_wprep(const float* __restrict__ W,
                                               short* __restrict__ Wt) {
    __shared__ float Ts[64][65];
    const int c = blockIdx.x;
    const int u = threadIdx.x;
    const int n4 = (u & 15) * 4;
    const int kr = u >> 4;
#pragma unroll
    for (int q = 0; q < 4; ++q) {
        const int kl = kr + q * 16;
        const int kg = c * 64 + kl;
        v4f v = {0.f, 0.f, 0.f, 0.f};
        if (kg < FIN) v = *(const v4f*)&W[(size_t)kg * HD + n4];
        *(v4f*)&Ts[kl][n4] = v;
    }
    __syncthreads();
    const int n = u >> 2;
    const int koff = (u & 3) * 16;
    __align__(16) short tmp[16];
#pragma unroll
    for (int r = 0; r < 16; ++r) tmp[r] = f2h16(Ts[koff + r][n]);
    *(uint4*)&Wt[(size_t)n * KP + c * 64 + koff]     = *(uint4*)&tmp[0];
    *(uint4*)&Wt[(size_t)n * KP + c * 64 + koff + 8] = *(uint4*)&tmp[8];
}

// ---------------- kernel 1: g = vert @ W, K-split x4 across blocks -----------
__global__ __launch_bounds__(256, 4) void k_gemm(
    const float* __restrict__ vert, const short* __restrict__ Wt,
    float* __restrict__ Cp)
{
    __shared__ float cacc[4][16][68];   // 17.4 KB

    const int t = threadIdx.x, lane = t & 63, w = t >> 6;
    const int ml = lane & 15, q = lane >> 4;
    const int i0 = blockIdx.x * 16;
    const int ks = blockIdx.y;
    const float* vrow = vert + (size_t)(i0 + ml) * FIN;

    v4f acc[4];
#pragma unroll
    for (int g = 0; g < 4; ++g) acc[g] = (v4f){0.f, 0.f, 0.f, 0.f};

    for (int c = ks + 4 * w; c < 45; c += 16) {
        const int k0 = c * 32 + q * 8;
        v4f a0, a1;
        if (k0 + 7 < FIN) {
            a0 = *(const v4f*)&vrow[k0];
            a1 = *(const v4f*)&vrow[k0 + 4];
        } else {
            float tmp[8];
#pragma unroll
            for (int e = 0; e < 8; ++e)
                tmp[e] = (k0 + e < FIN) ? vrow[k0 + e] : 0.f;
            a0 = (v4f){tmp[0], tmp[1], tmp[2], tmp[3]};
            a1 = (v4f){tmp[4], tmp[5], tmp[6], tmp[7]};
        }
        const f16x8 af = {(f16)a0.x, (f16)a0.y, (f16)a0.z, (f16)a0.w,
                          (f16)a1.x, (f16)a1.y, (f16)a1.z, (f16)a1.w};
#pragma unroll
        for (int g = 0; g < 4; ++g) {
            const f16x8 bf = *(const f16x8*)&Wt[(size_t)(g * 16 + ml) * KP + k0];
            acc[g] = __builtin_amdgcn_mfma_f32_16x16x32_f16(af, bf, acc[g], 0, 0, 0);
        }
    }

#pragma unroll
    for (int g = 0; g < 4; ++g)
#pragma unroll
        for (int r = 0; r < 4; ++r)
            cacc[w][q * 4 + r][g * 16 + ml] = acc[g][r];
    __syncthreads();

    const int m = t >> 4, n4 = (t & 15) * 4;
    v4f s = (v4f){0.f, 0.f, 0.f, 0.f};
#pragma unroll
    for (int ww = 0; ww < 4; ++ww) s += *(const v4f*)&cacc[ww][m][n4];
    *(v4f*)&Cp[((size_t)ks * NN + i0 + m) * HD + n4] = s;
}

// ---------------- kernel 1b: reduce K-partials + epilogue --------------------
__global__ __launch_bounds__(256) void k_gpost(
    const float* __restrict__ Cp,
    const float* __restrict__ al, const float* __restrict__ ar,
    short* __restrict__ gT, short* __restrict__ eB, short* __restrict__ eD,
    float* __restrict__ Rw)
{
    const int t = threadIdx.x;
    const int gid = blockIdx.x * 256 + t;        // 0 .. NN*16-1
    const int i = gid >> 4, n4 = (gid & 15) * 4;

    v4f s = (v4f){0.f, 0.f, 0.f, 0.f};
#pragma unroll
    for (int ks = 0; ks < NKS; ++ks)
        s += *(const v4f*)&Cp[((size_t)ks * NN + i) * HD + n4];

#pragma unroll
    for (int e = 0; e < 4; ++e)        // transposed store: gT[hd][node]
        gT[(size_t)(n4 + e) * NN + i] = f2h16(s[e]);

    float pl = s.x * al[n4] + s.y * al[n4 + 1] + s.z * al[n4 + 2] + s.w * al[n4 + 3];
    float pr = s.x * ar[n4] + s.y * ar[n4 + 1] + s.z * ar[n4 + 2] + s.w * ar[n4 + 3];
    pl += __shfl_xor(pl, 1, 64);
    pr += __shfl_xor(pr, 1, 64);
    if ((t & 1) == 0) {
        const int h = (t & 15) >> 1;
        eB[h * NN + i] = f2h16(exp2f(pr * LOG2E));          // exp(sr)
        eD[h * NN + i] = f2h16(exp2f(0.2f * pr * LOG2E));   // exp(0.2 sr)
        Rw[i * NH + h] = exp2f(-0.8f * pl * LOG2E);         // exp(-0.8 sl)
    }
}

// ---------------- kernel 2: MFMA flash-attn, ITB=32, 64j dbuf DMA ------------
// R7: i-tile 16 -> 32 rows/block. Same staged bytes per chunk now feed 2
// i-sub-tiles: 8 MFMA + ~120 VALU per wave per barrier (2x R6), G-fragments
// (B-operand, i-independent) reused across sub-tiles, total DMA halved.
// Grid (128, 8) = 1024 = 4 blocks/CU; LDS 20 KB dbuf.
__global__ __launch_bounds__(256, 4) void k_attn(
    const uint4* __restrict__ emask, const short* __restrict__ gT,
    const short* __restrict__ eB, const short* __restrict__ eD,
    const float* __restrict__ Rw,
    float* __restrict__ numw, float* __restrict__ denw)
{
    __shared__ __align__(16) short Gs[2][64 * 64];   // 2 x 8 KB, XOR-swizzled
    __shared__ __align__(16) short BDs[2][8 * 128];  // 2 x 2 KB: [h][B:64|D:64]

    const int t = threadIdx.x, lane = t & 63, w = t >> 6;
    const int ml = lane & 15, quad = lane >> 4;
    const int m8 = ml & 7;
    const int i0 = blockIdx.x * ITB;
    const int js = blockIdx.y;
    const int jbase = js * (NN / NJS);
    const int h0 = w, h1 = w + 4;
    const int qb4 = quad * 4;
    const bool mhi = (ml >= 8);
    const u32 one2 = 0x3C003C00u;                   // f16 {1.0, 1.0}
    const uint4 ones4 = (uint4){one2, one2, one2, one2};

    h2 Ri[2][2];                                    // [sub][head]
#pragma unroll
    for (int sub = 0; sub < 2; ++sub) {
        const f16 r0 = (f16)Rw[(i0 + sub * 16 + ml) * NH + h0];
        const f16 r1 = (f16)Rw[(i0 + sub * 16 + ml) * NH + h1];
        Ri[sub][0] = (h2){r0, r0};
        Ri[sub][1] = (h2){r1, r1};
    }

    // per-64j-chunk mask: uint2 {A word, B word}, one row per (sub, lane&15)
    const uint2* mrow0 = (const uint2*)emask + (size_t)(i0 + ml) * (NN / 64) + js * NCHK;
    const uint2* mrow1 = (const uint2*)emask + (size_t)(i0 + 16 + ml) * (NN / 64) + js * NCHK;

    // G staging: units u = t and 256+t; row = u>>3, col = (u&7)*8 ^ (row&7)*8
    const short *gsrc0, *gsrc1;
    {
        int u = t, row = u >> 3;
        gsrc0 = gT + (size_t)row * NN + jbase + (((u & 7) * 8) ^ ((row & 7) * 8));
        u = 256 + t; row = u >> 3;
        gsrc1 = gT + (size_t)row * NN + jbase + (((u & 7) * 8) ^ ((row & 7) * 8));
    }
    // BD staging (waves 0,1 only): unit t -> head t>>4, slot t&15 (0-7 B, 8-15 D)
    const short* bdsrc = nullptr;
    if (t < 128) {
        const int head = t >> 4, slot = t & 15;
        bdsrc = (slot < 8 ? eB : eD) + (size_t)head * NN + jbase + (slot & 7) * 8;
    }
    const int wub = (t & ~63) * 16;                  // wave-uniform dest base

#define STAGE(buf, ck)                                                        \
    do {                                                                      \
        const int jc_ = (ck) * 64;                                            \
        gload_lds16(gsrc0 + jc_, (char*)Gs[buf] + wub);                       \
        gload_lds16(gsrc1 + jc_, (char*)Gs[buf] + 4096 + wub);                \
        if (t < 128) gload_lds16(bdsrc + jc_, (char*)BDs[buf] + wub);         \
    } while (0)

    v4f acc[2][2];                                   // [sub][head]
#pragma unroll
    for (int sub = 0; sub < 2; ++sub) {
        acc[sub][0] = (v4f){0.f, 0.f, 0.f, 0.f};
        acc[sub][1] = (v4f){0.f, 0.f, 0.f, 0.f};
    }

    STAGE(0, 0);
    uint2 mw0 = mrow0[0], mw1 = mrow1[0], pm0, pm1;

    for (int c = 0; c < NCHK; ++c) {
        const int cb = c & 1, nb = cb ^ 1;
        __syncthreads();                  // drains vmcnt -> buf[cb] valid, nb free
        const bool pf = (c + 1) < NCHK;
        if (pf) {
            STAGE(nb, c + 1);
            pm0 = mrow0[c + 1];
            pm1 = mrow1[c + 1];
        }
#pragma unroll
        for (int s = 0; s < 2; ++s) {
            const int xj = s * 32 + quad * 8;          // 0..56
            const int xg = xj ^ (m8 * 8);              // read-side swizzle
            // B-operand (G fragments + ones col): i-independent, shared by subs
            union { uint4 u; f16x8 h; } g0u, g1u;
            g0u.u = mhi ? ones4 : *(const uint4*)&Gs[cb][(h0 * 8 + m8) * 64 + xg];
            g1u.u = mhi ? ones4 : *(const uint4*)&Gs[cb][(h1 * 8 + m8) * 64 + xg];
            const uint4 bu0 = *(const uint4*)&BDs[cb][h0 * 128 + xj];
            const uint4 du0 = *(const uint4*)&BDs[cb][h0 * 128 + 64 + xj];
            const uint4 bu1 = *(const uint4*)&BDs[cb][h1 * 128 + xj];
            const uint4 du1 = *(const uint4*)&BDs[cb][h1 * 128 + 64 + xj];
            const int base = (s << 4) + qb4;
#pragma unroll
            for (int sub = 0; sub < 2; ++sub) {
                const u32 WA = (sub ? mw1.x : mw0.x) >> base;   // even-j bits
                const u32 WB = (sub ? mw1.y : mw0.y) >> base;   // odd-j bits
                u32 m[4];
#pragma unroll
                for (int k = 0; k < 4; ++k) {
                    const int ea = SBFE1(WA, k);           // 0 or 0xFFFFFFFF
                    const int eb = SBFE1(WB, k);
                    m[k] = __builtin_amdgcn_perm((u32)eb, (u32)ea, 0x05040100u);
                }
                u32 aw0[4], aw1[4];
#pragma unroll
                for (int k = 0; k < 4; ++k) {
                    const u32 rd0 = h22u(Ri[sub][0] * u2h2((&du0.x)[k]));
                    const u32 rd1 = h22u(Ri[sub][1] * u2h2((&du1.x)[k]));
                    u32 p0, p1;
                    asm("v_pk_max_f16 %0, %1, %2" : "=v"(p0) : "v"(rd0), "v"((&bu0.x)[k]));
                    asm("v_pk_max_f16 %0, %1, %2" : "=v"(p1) : "v"(rd1), "v"((&bu1.x)[k]));
                    aw0[k] = p0 & m[k];
                    aw1[k] = p1 & m[k];
                }
                union { uint4 u; f16x8 h; } a0u, a1u;
                a0u.u = (uint4){aw0[0], aw0[1], aw0[2], aw0[3]};
                a1u.u = (uint4){aw1[0], aw1[1], aw1[2], aw1[3]};
                acc[sub][0] = __builtin_amdgcn_mfma_f32_16x16x32_f16(
                    a0u.h, g0u.h, acc[sub][0], 0, 0, 0);
                acc[sub][1] = __builtin_amdgcn_mfma_f32_16x16x32_f16(
                    a1u.h, g1u.h, acc[sub][1], 0, 0, 0);
            }
        }
        if (pf) { mw0 = pm0; mw1 = pm1; }
    }
#undef STAGE

    // partial store: col = ml (0..7 dims, 8 = denominator), row = quad*4 + r
    float* nw = numw + (size_t)js * NN * HD;
    float* dw = denw + (size_t)js * NN * NH;
#pragma unroll
    for (int sub = 0; sub < 2; ++sub) {
        const int ibase = i0 + sub * 16 + quad * 4;
#pragma unroll
        for (int hh = 0; hh < 2; ++hh) {
            const int h = w + hh * 4;
#pragma unroll
            for (int r = 0; r < 4; ++r) {
                if (ml < 8)       nw[(ibase + r) * HD + h * 8 + ml] = acc[sub][hh][r];
                else if (ml == 8) dw[(ibase + r) * NH + h]          = acc[sub][hh][r];
            }
        }
    }
}

// ---------------- kernel 3: combine j-split partials, div, ELU ---------------
__global__ __launch_bounds__(256) void k_comb(
    const float* __restrict__ numw, const float* __restrict__ denw,
    float* __restrict__ out)
{
    const int gid = blockIdx.x * 256 + threadIdx.x;   // 0 .. NN*HD-1
    const int i = gid >> 6, h = (gid & 63) >> 3;
    float num = 0.f, den = 0.f;
#pragma unroll
    for (int s = 0; s < NJS; ++s) {
        num += numw[(size_t)s * NN * HD + gid];
        den += denw[(size_t)s * NN * NH + i * NH + h];
    }
    float x = num / den;
    out[gid] = (x > 0.f) ? x : (__expf(x) - 1.f);     // ELU
}

extern "C" void kernel_launch(void* const* d_in, const int* in_sizes, int n_in,
                              void* d_out, int out_size, void* d_ws, size_t ws_size,
                              hipStream_t stream) {
    const float* vert = (const float*)d_in[0];
    const int*   edge = (const int*)d_in[1];
    const float* W    = (const float*)d_in[2];
    const float* al   = (const float*)d_in[3];
    const float* ar   = (const float*)d_in[4];
    float* out = (float*)d_out;

    char* ws = (char*)d_ws;
    short* gT    = (short*)ws;                          // 512 KB f16 g^T
    short* eB    = (short*)(ws + 512 * 1024);           // 64 KB
    short* eD    = (short*)(ws + 576 * 1024);           // 64 KB
    float* Rw    = (float*)(ws + 640 * 1024);           // 128 KB
    short* Wt    = (short*)(ws + 768 * 1024);           // 184 KB
    uint4* emask = (uint4*)(ws + 1024 * 1024);          // 2 MB edge bitmask
    float* Cp    = (float*)(ws + 3 * 1024 * 1024);      // 4 MB gemm K-partials
    float* numw  = (float*)(ws + 7 * 1024 * 1024);      // 8 MB (8 j-splits)
    float* denw  = (float*)(ws + 15 * 1024 * 1024);     // 1 MB

    hipLaunchKernelGGL(k_eprep, dim3(NN), dim3(256), 0, stream, edge, emask);
    hipLaunchKernelGGL(k_wprep, dim3(23), dim3(256), 0, stream, W, Wt);
    hipLaunchKernelGGL(k_gemm, dim3(NN / 16, NKS), dim3(256), 0, stream,
                       vert, Wt, Cp);
    hipLaunchKernelGGL(k_gpost, dim3(NN * 16 / 256), dim3(256), 0, stream,
                       Cp, al, ar, gT, eB, eD, Rw);
    hipLaunchKernelGGL(k_attn, dim3(NN / ITB, NJS), dim3(256), 0, stream,
                       emask, gT, eB, eD, Rw, numw, denw);
    hipLaunchKernelGGL(k_comb, dim3(NN * HD / 256), dim3(256), 0, stream,
                       numw, denw, out);
}

// Round 8
// 149.747 us; speedup vs baseline: 3.7292x; 1.0335x over previous
//
#include <hip/hip_runtime.h>
#include <hip/hip_bf16.h>

#define NN 4096      // n_nodes
#define FIN 1433     // in features
#define NH 8         // heads
#define DH 8         // per-head dim
#define HD 64        // NH*DH
#define KP 1472      // K padded to 46*32
#define LOG2E 1.44269504f
#define NJS 8        // j-splits
#define ITB 32       // i-rows per attn block
#define NCHK ((NN / NJS) / 64)    // 8 chunks of 64 j per block
#define NKS 4        // gemm K-splits: grid 1024 = 4 blocks/CU

typedef unsigned int u32;
typedef unsigned long long u64;
typedef float v4f __attribute__((ext_vector_type(4)));
typedef _Float16 f16;
typedef _Float16 h2 __attribute__((ext_vector_type(2)));
typedef _Float16 f16x8 __attribute__((ext_vector_type(8)));

static __device__ __forceinline__ short f2h16(float f) {
    union { f16 h; short s; } u; u.h = (f16)f; return u.s;
}
static __device__ __forceinline__ h2 u2h2(u32 x) {
    union { u32 u; h2 h; } v; v.u = x; return v.h;
}
static __device__ __forceinline__ u32 h22u(h2 x) {
    union { h2 h; u32 u; } v; v.h = x; return v.u;
}

#if __has_builtin(__builtin_amdgcn_sbfe)
#define SBFE1(x, k) __builtin_amdgcn_sbfe((int)(x), (k), 1)
#else
#define SBFE1(x, k) (((int)((x) << (31 - (k)))) >> 31)
#endif

// async global->LDS DMA, 16B per lane; LDS dest = wave-uniform base + lane*16.
static __device__ __forceinline__ void gload_lds16(const void* g, void* l) {
    __builtin_amdgcn_global_load_lds(
        (const __attribute__((address_space(1))) void*)g,
        (__attribute__((address_space(3))) void*)l, 16, 0, 0);
}

// ---------------- kernel 0: Wt[n][k] = f16(W[k][n]), k zero-padded to 1472 ---
__global__ __launch_bounds__(256) void k_wprep(const float* __restrict__ W,
                                               short* __restrict__ Wt) {
    __shared__ float Ts[64][65];
    const int c = blockIdx.x;
    const int u = threadIdx.x;
    const int n4 = (u & 15) * 4;
    const int kr = u >> 4;
#pragma unroll
    for (int q = 0; q < 4; ++q) {
        const int kl = kr + q * 16;
        const int kg = c * 64 + kl;
        v4f v = {0.f, 0.f, 0.f, 0.f};
        if (kg < FIN) v = *(const v4f*)&W[(size_t)kg * HD + n4];
        *(v4f*)&Ts[kl][n4] = v;
    }
    __syncthreads();
    const int n = u >> 2;
    const int koff = (u & 3) * 16;
    __align__(16) short tmp[16];
#pragma unroll
    for (int r = 0; r < 16; ++r) tmp[r] = f2h16(Ts[koff + r][n]);
    *(uint4*)&Wt[(size_t)n * KP + c * 64 + koff]     = *(uint4*)&tmp[0];
    *(uint4*)&Wt[(size_t)n * KP + c * 64 + koff + 8] = *(uint4*)&tmp[8];
}

// ---------------- kernel 1: g = vert @ W, K-split x4 across blocks -----------
__global__ __launch_bounds__(256, 4) void k_gemm(
    const float* __restrict__ vert, const short* __restrict__ Wt,
    float* __restrict__ Cp)
{
    __shared__ float cacc[4][16][68];   // 17.4 KB

    const int t = threadIdx.x, lane = t & 63, w = t >> 6;
    const int ml = lane & 15, q = lane >> 4;
    const int i0 = blockIdx.x * 16;
    const int ks = blockIdx.y;
    const float* vrow = vert + (size_t)(i0 + ml) * FIN;

    v4f acc[4];
#pragma unroll
    for (int g = 0; g < 4; ++g) acc[g] = (v4f){0.f, 0.f, 0.f, 0.f};

    for (int c = ks + 4 * w; c < 45; c += 16) {
        const int k0 = c * 32 + q * 8;
        v4f a0, a1;
        if (k0 + 7 < FIN) {
            a0 = *(const v4f*)&vrow[k0];
            a1 = *(const v4f*)&vrow[k0 + 4];
        } else {
            float tmp[8];
#pragma unroll
            for (int e = 0; e < 8; ++e)
                tmp[e] = (k0 + e < FIN) ? vrow[k0 + e] : 0.f;
            a0 = (v4f){tmp[0], tmp[1], tmp[2], tmp[3]};
            a1 = (v4f){tmp[4], tmp[5], tmp[6], tmp[7]};
        }
        const f16x8 af = {(f16)a0.x, (f16)a0.y, (f16)a0.z, (f16)a0.w,
                          (f16)a1.x, (f16)a1.y, (f16)a1.z, (f16)a1.w};
#pragma unroll
        for (int g = 0; g < 4; ++g) {
            const f16x8 bf = *(const f16x8*)&Wt[(size_t)(g * 16 + ml) * KP + k0];
            acc[g] = __builtin_amdgcn_mfma_f32_16x16x32_f16(af, bf, acc[g], 0, 0, 0);
        }
    }

#pragma unroll
    for (int g = 0; g < 4; ++g)
#pragma unroll
        for (int r = 0; r < 4; ++r)
            cacc[w][q * 4 + r][g * 16 + ml] = acc[g][r];
    __syncthreads();

    const int m = t >> 4, n4 = (t & 15) * 4;
    v4f s = (v4f){0.f, 0.f, 0.f, 0.f};
#pragma unroll
    for (int ww = 0; ww < 4; ++ww) s += *(const v4f*)&cacc[ww][m][n4];
    *(v4f*)&Cp[((size_t)ks * NN + i0 + m) * HD + n4] = s;
}

// ---------------- kernel 1b: reduce K-partials + epilogue --------------------
__global__ __launch_bounds__(256) void k_gpost(
    const float* __restrict__ Cp,
    const float* __restrict__ al, const float* __restrict__ ar,
    short* __restrict__ gT, short* __restrict__ eB, short* __restrict__ eD,
    float* __restrict__ Rw)
{
    const int t = threadIdx.x;
    const int gid = blockIdx.x * 256 + t;        // 0 .. NN*16-1
    const int i = gid >> 4, n4 = (gid & 15) * 4;

    v4f s = (v4f){0.f, 0.f, 0.f, 0.f};
#pragma unroll
    for (int ks = 0; ks < NKS; ++ks)
        s += *(const v4f*)&Cp[((size_t)ks * NN + i) * HD + n4];

#pragma unroll
    for (int e = 0; e < 4; ++e)        // transposed store: gT[hd][node]
        gT[(size_t)(n4 + e) * NN + i] = f2h16(s[e]);

    float pl = s.x * al[n4] + s.y * al[n4 + 1] + s.z * al[n4 + 2] + s.w * al[n4 + 3];
    float pr = s.x * ar[n4] + s.y * ar[n4 + 1] + s.z * ar[n4 + 2] + s.w * ar[n4 + 3];
    pl += __shfl_xor(pl, 1, 64);
    pr += __shfl_xor(pr, 1, 64);
    if ((t & 1) == 0) {
        const int h = (t & 15) >> 1;
        eB[h * NN + i] = f2h16(exp2f(pr * LOG2E));          // exp(sr)
        eD[h * NN + i] = f2h16(exp2f(0.2f * pr * LOG2E));   // exp(0.2 sr)
        Rw[i * NH + h] = exp2f(-0.8f * pl * LOG2E);         // exp(-0.8 sl)
    }
}

// ---------------- kernel 2: MFMA flash-attn, inline edge-ballot --------------
// R8: eprep DELETED. attn ingests the raw 67 MB edge stream itself (R0 proved
// the stall budget absorbs it: R0 attn 43.5 µs with edge inline vs R7's
// 36 + 11 eprep). Per 64-j chunk, wave w loads 8 edge rows as coalesced
// NONTEMPORAL dwords (no L2 thrash of gT), ballots to natural-order u64
// masks, stages them dbuf in LDS next to G/BD. Loads issue with STAGE
// (early); ballot+ds_write after compute (T14 split). Decode: 8-bit field
// at j-offset quad*8, sbfe pairs — same cost as the old emask decode.
__global__ __launch_bounds__(256, 4) void k_attn(
    const int* __restrict__ edge, const short* __restrict__ gT,
    const short* __restrict__ eB, const short* __restrict__ eD,
    const float* __restrict__ Rw,
    float* __restrict__ numw, float* __restrict__ denw)
{
    __shared__ __align__(16) short Gs[2][64 * 64];   // 2 x 8 KB, XOR-swizzled
    __shared__ __align__(16) short BDs[2][8 * 128];  // 2 x 2 KB: [h][B:64|D:64]
    __shared__ __align__(16) u64 Ms[2][ITB];         // 2 x 256 B edge masks

    const int t = threadIdx.x, lane = t & 63, w = t >> 6;
    const int ml = lane & 15, quad = lane >> 4;
    const int m8 = ml & 7;
    const int i0 = blockIdx.x * ITB;
    const int js = blockIdx.y;
    const int jbase = js * (NN / NJS);
    const int h0 = w, h1 = w + 4;
    const bool mhi = (ml >= 8);
    const u32 one2 = 0x3C003C00u;                   // f16 {1.0, 1.0}
    const uint4 ones4 = (uint4){one2, one2, one2, one2};

    h2 Ri[2][2];                                    // [sub][head]
#pragma unroll
    for (int sub = 0; sub < 2; ++sub) {
        const f16 r0 = (f16)Rw[(i0 + sub * 16 + ml) * NH + h0];
        const f16 r1 = (f16)Rw[(i0 + sub * 16 + ml) * NH + h1];
        Ri[sub][0] = (h2){r0, r0};
        Ri[sub][1] = (h2){r1, r1};
    }

    // G staging: units u = t and 256+t; row = u>>3, col = (u&7)*8 ^ (row&7)*8
    const short *gsrc0, *gsrc1;
    {
        int u = t, row = u >> 3;
        gsrc0 = gT + (size_t)row * NN + jbase + (((u & 7) * 8) ^ ((row & 7) * 8));
        u = 256 + t; row = u >> 3;
        gsrc1 = gT + (size_t)row * NN + jbase + (((u & 7) * 8) ^ ((row & 7) * 8));
    }
    // BD staging (waves 0,1 only): unit t -> head t>>4, slot t&15 (0-7 B, 8-15 D)
    const short* bdsrc = nullptr;
    if (t < 128) {
        const int head = t >> 4, slot = t & 15;
        bdsrc = (slot < 8 ? eB : eD) + (size_t)head * NN + jbase + (slot & 7) * 8;
    }
    const int wub = (t & ~63) * 16;                  // wave-uniform dest base

    // edge: wave w owns rows i0 + w*8 + rr; lane = j-offset within chunk
    const int* ebase = edge + (size_t)(i0 + w * 8) * NN + jbase + lane;
    u32 er[8];

#define STAGE(buf, ck)                                                        \
    do {                                                                      \
        const int jc_ = (ck) * 64;                                            \
        gload_lds16(gsrc0 + jc_, (char*)Gs[buf] + wub);                       \
        gload_lds16(gsrc1 + jc_, (char*)Gs[buf] + 4096 + wub);                \
        if (t < 128) gload_lds16(bdsrc + jc_, (char*)BDs[buf] + wub);         \
    } while (0)

#define ELOAD(ck)                                                             \
    do {                                                                      \
        const int jo_ = (ck) * 64;                                            \
        _Pragma("unroll")                                                     \
        for (int rr = 0; rr < 8; ++rr)                                        \
            er[rr] = __builtin_nontemporal_load(ebase + (size_t)rr * NN + jo_); \
    } while (0)

#define EBALLOT(buf)                                                          \
    do {                                                                      \
        _Pragma("unroll")                                                     \
        for (int rr = 0; rr < 8; ++rr) {                                      \
            const u64 b_ = __ballot(er[rr] != 0);                             \
            if (lane == 0) Ms[buf][w * 8 + rr] = b_;                          \
        }                                                                     \
    } while (0)

    v4f acc[2][2];                                   // [sub][head]
#pragma unroll
    for (int sub = 0; sub < 2; ++sub) {
        acc[sub][0] = (v4f){0.f, 0.f, 0.f, 0.f};
        acc[sub][1] = (v4f){0.f, 0.f, 0.f, 0.f};
    }

    STAGE(0, 0);
    ELOAD(0);
    EBALLOT(0);

    for (int c = 0; c < NCHK; ++c) {
        const int cb = c & 1, nb = cb ^ 1;
        __syncthreads();                  // drains vm+lgkm: buf[cb]+Ms[cb] valid
        const bool pf = (c + 1) < NCHK;
        if (pf) { STAGE(nb, c + 1); ELOAD(c + 1); }

        // masks for this chunk: row i0+ml (sub0), i0+16+ml (sub1), natural j order
        union { u64 q; uint2 d; } m0u, m1u;
        m0u.q = Ms[cb][ml];
        m1u.q = Ms[cb][16 + ml];

#pragma unroll
        for (int s = 0; s < 2; ++s) {
            const int xj = s * 32 + quad * 8;          // 0..56
            const int xg = xj ^ (m8 * 8);              // read-side swizzle
            // B-operand (G fragments + ones col): i-independent, shared by subs
            union { uint4 u; f16x8 h; } g0u, g1u;
            g0u.u = mhi ? ones4 : *(const uint4*)&Gs[cb][(h0 * 8 + m8) * 64 + xg];
            g1u.u = mhi ? ones4 : *(const uint4*)&Gs[cb][(h1 * 8 + m8) * 64 + xg];
            const uint4 bu0 = *(const uint4*)&BDs[cb][h0 * 128 + xj];
            const uint4 du0 = *(const uint4*)&BDs[cb][h0 * 128 + 64 + xj];
            const uint4 bu1 = *(const uint4*)&BDs[cb][h1 * 128 + xj];
            const uint4 du1 = *(const uint4*)&BDs[cb][h1 * 128 + 64 + xj];
#pragma unroll
            for (int sub = 0; sub < 2; ++sub) {
                const u32 half = sub ? ((s ? m1u.d.y : m1u.d.x))
                                     : ((s ? m0u.d.y : m0u.d.x));
                const u32 w8 = half >> (quad * 8);     // 8 j-bits for this lane
                u32 m[4];
#pragma unroll
                for (int k = 0; k < 4; ++k) {
                    const int ea = SBFE1(w8, 2 * k);       // 0 or 0xFFFFFFFF
                    const int eb = SBFE1(w8, 2 * k + 1);
                    m[k] = __builtin_amdgcn_perm((u32)eb, (u32)ea, 0x05040100u);
                }
                u32 aw0[4], aw1[4];
#pragma unroll
                for (int k = 0; k < 4; ++k) {
                    const u32 rd0 = h22u(Ri[sub][0] * u2h2((&du0.x)[k]));
                    const u32 rd1 = h22u(Ri[sub][1] * u2h2((&du1.x)[k]));
                    u32 p0, p1;
                    asm("v_pk_max_f16 %0, %1, %2" : "=v"(p0) : "v"(rd0), "v"((&bu0.x)[k]));
                    asm("v_pk_max_f16 %0, %1, %2" : "=v"(p1) : "v"(rd1), "v"((&bu1.x)[k]));
                    aw0[k] = p0 & m[k];
                    aw1[k] = p1 & m[k];
                }
                union { uint4 u; f16x8 h; } a0u, a1u;
                a0u.u = (uint4){aw0[0], aw0[1], aw0[2], aw0[3]};
                a1u.u = (uint4){aw1[0], aw1[1], aw1[2], aw1[3]};
                acc[sub][0] = __builtin_amdgcn_mfma_f32_16x16x32_f16(
                    a0u.h, g0u.h, acc[sub][0], 0, 0, 0);
                acc[sub][1] = __builtin_amdgcn_mfma_f32_16x16x32_f16(
                    a1u.h, g1u.h, acc[sub][1], 0, 0, 0);
            }
        }
        if (pf) EBALLOT(nb);              // er loaded by now; write next masks
    }
#undef STAGE
#undef ELOAD
#undef EBALLOT

    // partial store: col = ml (0..7 dims, 8 = denominator), row = quad*4 + r
    float* nw = numw + (size_t)js * NN * HD;
    float* dw = denw + (size_t)js * NN * NH;
#pragma unroll
    for (int sub = 0; sub < 2; ++sub) {
        const int ibase = i0 + sub * 16 + quad * 4;
#pragma unroll
        for (int hh = 0; hh < 2; ++hh) {
            const int h = w + hh * 4;
#pragma unroll
            for (int r = 0; r < 4; ++r) {
                if (ml < 8)       nw[(ibase + r) * HD + h * 8 + ml] = acc[sub][hh][r];
                else if (ml == 8) dw[(ibase + r) * NH + h]          = acc[sub][hh][r];
            }
        }
    }
}

// ---------------- kernel 3: combine j-split partials, div, ELU ---------------
__global__ __launch_bounds__(256) void k_comb(
    const float* __restrict__ numw, const float* __restrict__ denw,
    float* __restrict__ out)
{
    const int gid = blockIdx.x * 256 + threadIdx.x;   // 0 .. NN*HD-1
    const int i = gid >> 6, h = (gid & 63) >> 3;
    float num = 0.f, den = 0.f;
#pragma unroll
    for (int s = 0; s < NJS; ++s) {
        num += numw[(size_t)s * NN * HD + gid];
        den += denw[(size_t)s * NN * NH + i * NH + h];
    }
    float x = num / den;
    out[gid] = (x > 0.f) ? x : (__expf(x) - 1.f);     // ELU
}

extern "C" void kernel_launch(void* const* d_in, const int* in_sizes, int n_in,
                              void* d_out, int out_size, void* d_ws, size_t ws_size,
                              hipStream_t stream) {
    const float* vert = (const float*)d_in[0];
    const int*   edge = (const int*)d_in[1];
    const float* W    = (const float*)d_in[2];
    const float* al   = (const float*)d_in[3];
    const float* ar   = (const float*)d_in[4];
    float* out = (float*)d_out;

    char* ws = (char*)d_ws;
    short* gT    = (short*)ws;                          // 512 KB f16 g^T
    short* eB    = (short*)(ws + 512 * 1024);           // 64 KB
    short* eD    = (short*)(ws + 576 * 1024);           // 64 KB
    float* Rw    = (float*)(ws + 640 * 1024);           // 128 KB
    short* Wt    = (short*)(ws + 768 * 1024);           // 184 KB
    float* Cp    = (float*)(ws + 3 * 1024 * 1024);      // 4 MB gemm K-partials
    float* numw  = (float*)(ws + 7 * 1024 * 1024);      // 8 MB (8 j-splits)
    float* denw  = (float*)(ws + 15 * 1024 * 1024);     // 1 MB

    hipLaunchKernelGGL(k_wprep, dim3(23), dim3(256), 0, stream, W, Wt);
    hipLaunchKernelGGL(k_gemm, dim3(NN / 16, NKS), dim3(256), 0, stream,
                       vert, Wt, Cp);
    hipLaunchKernelGGL(k_gpost, dim3(NN * 16 / 256), dim3(256), 0, stream,
                       Cp, al, ar, gT, eB, eD, Rw);
    hipLaunchKernelGGL(k_attn, dim3(NN / ITB, NJS), dim3(256), 0, stream,
                       edge, gT, eB, eD, Rw, numw, denw);
    hipLaunchKernelGGL(k_comb, dim3(NN * HD / 256), dim3(256), 0, stream,
                       numw, denw, out);
}